// Round 3
// baseline (372.486 us; speedup 1.0000x reference)
//
#include <hip/hip_runtime.h>
#include <hip/hip_bf16.h>
#include <hip/hip_cooperative_groups.h>
#include <math.h>

#define LL 8192
#define CC 256
#define SS 16
#define NJ (CC*SS)      // 4096 chains
#define GG 256          // chunks == blocks (cooperative, 1 block/CU)
#define TT 32           // rows per chunk
#define THREADS 512
#define SEGS 16
#define PER (GG/SEGS)   // 16 chunks per carry segment

#define LOG2E 1.4426950408889634f
#define LN2   0.6931471805599453f

#define XSTR 264        // x tile LDS stride (shorts), pad 8
#define WSTR 264        // W tile LDS stride (shorts)
#define DSTR 260        // dt tile LDS stride (floats), pad 4

typedef __attribute__((ext_vector_type(8))) short short8;
typedef __attribute__((ext_vector_type(4))) float floatx4;

__device__ __forceinline__ float fexp2(float v){ return __builtin_amdgcn_exp2f(v); }
__device__ __forceinline__ float flog2v(float v){ return __builtin_amdgcn_logf(v); }

__device__ __forceinline__ float softplus(float z){
    float t = fexp2(-fabsf(z) * LOG2E);
    return fmaxf(z, 0.f) + LN2 * flog2v(1.f + t);
}

__device__ __forceinline__ unsigned short f2b(float f){
    __hip_bfloat16 h = __float2bfloat16(f);
    return *(unsigned short*)&h;
}
__device__ __forceinline__ float b2f(unsigned short u){
    __hip_bfloat16 h = *(__hip_bfloat16*)&u;
    return __bfloat162float(h);
}

// One cooperative kernel: block g = chunk g (rows 32g..32g+31).
// Phase 1: split-bf16 MFMA GEMM (M=32,N=288,K=256) -> dt/boa/cm in LDS only.
// Phase 2: local scan -> per-chunk aggregates Ap/Hl (global).
// grid.sync
// Phase 3: k_carry (tid<256) -> Cr (global).
// grid.sync
// Phase 4: apply carry, contract to y.
// NOTE: no runtime-indexed thread-private arrays anywhere (rule #20) —
// x is re-read through a pointer (L2-resident), NOT cached in a reg array.
__global__ __launch_bounds__(THREADS, 2) void k_fused(
    const float* __restrict__ x, const float* __restrict__ logA,
    const float* __restrict__ Wdt, const float* __restrict__ bdt,
    const float* __restrict__ WB,  const float* __restrict__ bB,
    const float* __restrict__ WC,  const float* __restrict__ bC,
    float* __restrict__ Ap, float* __restrict__ Hl, float* __restrict__ Cr,
    float* __restrict__ y)
{
    __shared__ unsigned short xh[32*XSTR];   // 16.9 KB
    __shared__ unsigned short xl[32*XSTR];   // 16.9 KB
    __shared__ unsigned short Wh2[64*WSTR];  // 33.8 KB
    __shared__ unsigned short Wl2[64*WSTR];  // 33.8 KB
    __shared__ float dtS[32*DSTR];           // 33.3 KB
    __shared__ float boaS[32*SS];            // 2 KB
    __shared__ float cmS[32*SS];             // 2 KB
    __shared__ float As[SEGS][17], Us[SEGS][17];  // 2.2 KB   (total ~138 KB)

    const int tid  = threadIdx.x;
    const int g    = blockIdx.x;
    const int row0 = g * TT;

    // ---------------- phase 1a: stage x tile (32x256) as bf16 hi/lo ----------
    #pragma unroll
    for (int j = 0; j < 4; j++){
        int idx = tid + j*THREADS;           // 2048 float4-groups
        int r   = idx >> 6;
        int kq  = (idx & 63) * 4;
        float4 f = *(const float4*)&x[(size_t)(row0+r)*CC + kq];
        float fv[4] = {f.x, f.y, f.z, f.w};
        unsigned short hs[4], ls[4];
        #pragma unroll
        for (int i=0;i<4;i++){ hs[i]=f2b(fv[i]); ls[i]=f2b(fv[i]-b2f(hs[i])); }
        uint2 ph, pl;
        ph.x = (unsigned)hs[0] | ((unsigned)hs[1] << 16);
        ph.y = (unsigned)hs[2] | ((unsigned)hs[3] << 16);
        pl.x = (unsigned)ls[0] | ((unsigned)ls[1] << 16);
        pl.y = (unsigned)ls[2] | ((unsigned)ls[3] << 16);
        *(uint2*)&xh[r*XSTR + kq] = ph;
        *(uint2*)&xl[r*XSTR + kq] = pl;
    }

    const int lane = tid & 63;
    const int wv   = tid >> 6;      // 0..7
    const int m16  = lane & 15;
    const int q    = lane >> 4;
    const int mi   = wv & 1;        // M-frag (rows mi*16..+16)
    const int ni   = wv >> 1;       // N-frag within 64-col supertile

    const int cw = tid & 63;        // staging col within supertile
    const int kb = (tid >> 6) * 32; // staging k-group

    // ---------------- phase 1b: GEMM over 5 supertiles of 64 cols ------------
    for (int nt = 0; nt < 5; nt++){
        {   // stage W^T tile: [64 cols][256 k] bf16 hi/lo
            int bcol = nt*64 + cw;
            const float* wp = nullptr; int wstr = 0;
            if (bcol < 256)      { wp = Wdt + bcol;       wstr = CC; }
            else if (bcol < 272) { wp = WB  + (bcol-256); wstr = SS; }
            else if (bcol < 288) { wp = WC  + (bcol-272); wstr = SS; }
            if (wp){
                #pragma unroll
                for (int i8 = 0; i8 < 32; i8 += 8){
                    unsigned short hs[8], ls[8];
                    #pragma unroll
                    for (int u = 0; u < 8; u++){
                        float v = wp[(size_t)(kb+i8+u)*wstr];
                        hs[u] = f2b(v);
                        ls[u] = f2b(v - b2f(hs[u]));
                    }
                    uint4 ph, pl;
                    ph.x = (unsigned)hs[0] | ((unsigned)hs[1] << 16);
                    ph.y = (unsigned)hs[2] | ((unsigned)hs[3] << 16);
                    ph.z = (unsigned)hs[4] | ((unsigned)hs[5] << 16);
                    ph.w = (unsigned)hs[6] | ((unsigned)hs[7] << 16);
                    pl.x = (unsigned)ls[0] | ((unsigned)ls[1] << 16);
                    pl.y = (unsigned)ls[2] | ((unsigned)ls[3] << 16);
                    pl.z = (unsigned)ls[4] | ((unsigned)ls[5] << 16);
                    pl.w = (unsigned)ls[6] | ((unsigned)ls[7] << 16);
                    *(uint4*)&Wh2[cw*WSTR + kb + i8] = ph;
                    *(uint4*)&Wl2[cw*WSTR + kb + i8] = pl;
                }
            }
        }
        __syncthreads();

        if (nt < 4 || ni < 2){
            floatx4 acc = (floatx4){0.f,0.f,0.f,0.f};
            #pragma unroll
            for (int ks = 0; ks < 256; ks += 32){
                short8 bh = *(const short8*)&Wh2[(ni*16+m16)*WSTR + ks + q*8];
                short8 bl = *(const short8*)&Wl2[(ni*16+m16)*WSTR + ks + q*8];
                short8 ah = *(const short8*)&xh [(mi*16+m16)*XSTR + ks + q*8];
                short8 al = *(const short8*)&xl [(mi*16+m16)*XSTR + ks + q*8];
                acc = __builtin_amdgcn_mfma_f32_16x16x32_bf16(al, bh, acc, 0, 0, 0);
                acc = __builtin_amdgcn_mfma_f32_16x16x32_bf16(ah, bl, acc, 0, 0, 0);
                acc = __builtin_amdgcn_mfma_f32_16x16x32_bf16(ah, bh, acc, 0, 0, 0);
            }
            int col   = nt*64 + ni*16 + m16;
            int rbase = mi*16 + q*4;
            if (col < 256){
                float bias = bdt[col];
                #pragma unroll
                for (int r=0;r<4;r++)
                    dtS[(rbase+r)*DSTR + col] = softplus(0.01f + acc[r] + bias);
            } else if (col < 272){
                int s = col - 256;
                float A  = -fexp2(logA[s]*LOG2E);
                float sc = LOG2E / A;
                float bias = bB[s];
                #pragma unroll
                for (int r=0;r<4;r++)
                    boaS[(rbase+r)*SS + s] = (1.f + acc[r] + bias) * sc;
            } else {
                int s = col - 272;
                float bias = bC[s];
                #pragma unroll
                for (int r=0;r<4;r++)
                    cmS[(rbase+r)*SS + s] = acc[r] + bias;
            }
        }
        __syncthreads();
    }

    // ---------------- phase 2: local scan -> aggregates ----------------------
    const int c  = tid >> 1;        // channel 0..255
    const int sb = (tid & 1) * 8;   // state sub-block {0,8}

    float Al2v[8];
    #pragma unroll
    for (int i=0;i<8;i++) Al2v[i] = -fexp2(logA[sb+i]*LOG2E) * LOG2E;

    const float* __restrict__ xp = x + (size_t)row0*CC + c;

    float Apr[8], h[8];
    #pragma unroll
    for (int i=0;i<8;i++){ Apr[i]=1.f; h[i]=0.f; }

    #pragma unroll 8
    for (int t=0;t<TT;t++){
        float d  = dtS[t*DSTR + c];
        float xv = xp[(size_t)t*CC];
        float4 b0 = *(const float4*)&boaS[t*SS + sb];
        float4 b1 = *(const float4*)&boaS[t*SS + sb + 4];
        float bo[8] = {b0.x,b0.y,b0.z,b0.w,b1.x,b1.y,b1.z,b1.w};
        #pragma unroll
        for (int s=0;s<8;s++){
            float a = fexp2(d * Al2v[s]);
            float u = fexp2(fmaf(a, bo[s], -bo[s])) * xv;
            h[s] = fmaf(a, h[s], u);
            Apr[s] *= a;
        }
    }
    {
        const size_t base = (size_t)g*NJ + (size_t)c*SS + sb;
        *(float4*)&Ap[base]   = make_float4(Apr[0],Apr[1],Apr[2],Apr[3]);
        *(float4*)&Ap[base+4] = make_float4(Apr[4],Apr[5],Apr[6],Apr[7]);
        *(float4*)&Hl[base]   = make_float4(h[0],h[1],h[2],h[3]);
        *(float4*)&Hl[base+4] = make_float4(h[4],h[5],h[6],h[7]);
    }

    __threadfence();
    cooperative_groups::this_grid().sync();
    __threadfence();

    // ---------------- phase 3: carry (tid<256, same layout as k_carry) -------
    float a2[PER], u2[PER];
    const int jl  = tid & 15;
    const int seg = (tid >> 4) & 15;
    const size_t cb = (size_t)(seg*PER)*NJ + (size_t)(g*16 + jl);
    if (tid < 256){
        #pragma unroll
        for (int k=0;k<PER;k++){
            a2[k] = Ap[cb + (size_t)k*NJ];
            u2[k] = Hl[cb + (size_t)k*NJ];
        }
        float Aag = 1.f, Uag = 0.f;
        #pragma unroll
        for (int k=0;k<PER;k++){ Uag = fmaf(a2[k], Uag, u2[k]); Aag *= a2[k]; }
        As[seg][jl] = Aag; Us[seg][jl] = Uag;
    }
    __syncthreads();
    if (tid < 256){
        float hin = 0.f;
        for (int t2 = 0; t2 < seg; ++t2)
            hin = fmaf(As[t2][jl], hin, Us[t2][jl]);
        float hh = hin;
        #pragma unroll
        for (int k=0;k<PER;k++){
            Cr[cb + (size_t)k*NJ] = hh;
            hh = fmaf(a2[k], hh, u2[k]);
        }
    }

    __threadfence();
    cooperative_groups::this_grid().sync();
    __threadfence();

    // ---------------- phase 4: apply carry, contract to y --------------------
    float hh[8];
    {
        const size_t base = (size_t)g*NJ + (size_t)c*SS + sb;
        float4 h0 = *(const float4*)&Cr[base];
        float4 h1 = *(const float4*)&Cr[base+4];
        hh[0]=h0.x; hh[1]=h0.y; hh[2]=h0.z; hh[3]=h0.w;
        hh[4]=h1.x; hh[5]=h1.y; hh[6]=h1.z; hh[7]=h1.w;
    }

    #pragma unroll 8
    for (int t=0;t<TT;t++){
        float d  = dtS[t*DSTR + c];
        float xv = xp[(size_t)t*CC];
        float4 b0 = *(const float4*)&boaS[t*SS + sb];
        float4 b1 = *(const float4*)&boaS[t*SS + sb + 4];
        float4 c0 = *(const float4*)&cmS [t*SS + sb];
        float4 c1 = *(const float4*)&cmS [t*SS + sb + 4];
        float bo[8] = {b0.x,b0.y,b0.z,b0.w,b1.x,b1.y,b1.z,b1.w};
        float cv[8] = {c0.x,c0.y,c0.z,c0.w,c1.x,c1.y,c1.z,c1.w};
        float yv = 0.f;
        #pragma unroll
        for (int s=0;s<8;s++){
            float a = fexp2(d * Al2v[s]);
            float u = fexp2(fmaf(a, bo[s], -bo[s])) * xv;
            hh[s] = fmaf(a, hh[s], u);
            yv = fmaf(cv[s], hh[s], yv);
        }
        yv += __shfl_xor(yv, 1);
        if ((tid & 1) == 0) y[(size_t)(row0+t)*CC + c] = yv;
    }
}

extern "C" void kernel_launch(void* const* d_in, const int* in_sizes, int n_in,
                              void* d_out, int out_size, void* d_ws, size_t ws_size,
                              hipStream_t stream) {
    const float* x    = (const float*)d_in[0];
    const float* logA = (const float*)d_in[1];
    const float* W_dt = (const float*)d_in[2];
    const float* b_dt = (const float*)d_in[3];
    const float* W_B  = (const float*)d_in[4];
    const float* b_B  = (const float*)d_in[5];
    const float* W_C  = (const float*)d_in[6];
    const float* b_C  = (const float*)d_in[7];
    float* y  = (float*)d_out;
    float* ws = (float*)d_ws;

    float* Ap = ws;                          // GG*NJ = 1M floats (4 MB)
    float* Hl = Ap + (size_t)GG*NJ;          // 4 MB
    float* Cr = Hl + (size_t)GG*NJ;          // 4 MB

    void* args[] = {
        (void*)&x, (void*)&logA,
        (void*)&W_dt, (void*)&b_dt,
        (void*)&W_B, (void*)&b_B,
        (void*)&W_C, (void*)&b_C,
        (void*)&Ap, (void*)&Hl, (void*)&Cr, (void*)&y
    };
    hipLaunchCooperativeKernel((void*)k_fused, dim3(GG), dim3(THREADS),
                               args, 0, stream);
}

// Round 4
// 119.708 us; speedup vs baseline: 3.1116x; 3.1116x over previous
//
#include <hip/hip_runtime.h>
#include <hip/hip_bf16.h>
#include <math.h>

#define LL 8192
#define CC 256
#define SS 16
#define NJ (CC*SS)      // 4096 chains
#define GG 256          // chunks
#define TT 32           // rows per chunk
#define THREADS 512
#define SEGS 16
#define PER (GG/SEGS)   // 16 chunks per carry segment
#define SP 4            // states per thread (k_scan2)
#define CB 64           // channels per block (k_scan2)

#define LOG2E 1.4426950408889634f
#define LN2   0.6931471805599453f

#define XSTR 264        // x tile LDS stride (shorts), pad 8
#define WSTR 264        // W tile LDS stride (shorts)
#define DSTR 260        // dt tile LDS stride (floats), pad 4

typedef __attribute__((ext_vector_type(8))) short short8;
typedef __attribute__((ext_vector_type(4))) float floatx4;

__device__ __forceinline__ float fexp2(float v){ return __builtin_amdgcn_exp2f(v); }
__device__ __forceinline__ float flog2v(float v){ return __builtin_amdgcn_logf(v); }

__device__ __forceinline__ float softplus(float z){
    float t = fexp2(-fabsf(z) * LOG2E);
    return fmaxf(z, 0.f) + LN2 * flog2v(1.f + t);
}

__device__ __forceinline__ unsigned short f2b(float f){
    __hip_bfloat16 h = __float2bfloat16(f);
    return *(unsigned short*)&h;
}
__device__ __forceinline__ float b2f(unsigned short u){
    __hip_bfloat16 h = *(__hip_bfloat16*)&u;
    return __bfloat162float(h);
}

// ============ K1: per-chunk GEMM (LDS-resident) + local scan =================
// Block g = chunk g (rows 32g..32g+31). Regular launch, no grid sync.
// Phase 1: split-bf16 MFMA GEMM (M=32,N=288,K=256) -> dt/boa/cm in LDS,
//          ALSO written to global for K3.
// Phase 2: local scan from LDS -> per-chunk aggregates Ap/Hl (global).
__global__ __launch_bounds__(THREADS, 2) void k_mmscan(
    const float* __restrict__ x, const float* __restrict__ logA,
    const float* __restrict__ Wdt, const float* __restrict__ bdt,
    const float* __restrict__ WB,  const float* __restrict__ bB,
    const float* __restrict__ WC,  const float* __restrict__ bC,
    float* __restrict__ dt, float* __restrict__ boa, float* __restrict__ cm,
    float* __restrict__ Ap, float* __restrict__ Hl)
{
    __shared__ unsigned short xh[32*XSTR];   // 16.9 KB
    __shared__ unsigned short xl[32*XSTR];   // 16.9 KB
    __shared__ unsigned short Wh2[64*WSTR];  // 33.8 KB
    __shared__ unsigned short Wl2[64*WSTR];  // 33.8 KB
    __shared__ float dtS[32*DSTR];           // 33.3 KB
    __shared__ float boaS[32*SS];            // 2 KB
    __shared__ float cmS[32*SS];             // 2 KB

    const int tid  = threadIdx.x;
    const int g    = blockIdx.x;
    const int row0 = g * TT;

    // ---------------- phase 1a: stage x tile (32x256) as bf16 hi/lo ----------
    #pragma unroll
    for (int j = 0; j < 4; j++){
        int idx = tid + j*THREADS;           // 2048 float4-groups
        int r   = idx >> 6;
        int kq  = (idx & 63) * 4;
        float4 f = *(const float4*)&x[(size_t)(row0+r)*CC + kq];
        float fv[4] = {f.x, f.y, f.z, f.w};
        unsigned short hs[4], ls[4];
        #pragma unroll
        for (int i=0;i<4;i++){ hs[i]=f2b(fv[i]); ls[i]=f2b(fv[i]-b2f(hs[i])); }
        uint2 ph, pl;
        ph.x = (unsigned)hs[0] | ((unsigned)hs[1] << 16);
        ph.y = (unsigned)hs[2] | ((unsigned)hs[3] << 16);
        pl.x = (unsigned)ls[0] | ((unsigned)ls[1] << 16);
        pl.y = (unsigned)ls[2] | ((unsigned)ls[3] << 16);
        *(uint2*)&xh[r*XSTR + kq] = ph;
        *(uint2*)&xl[r*XSTR + kq] = pl;
    }

    const int lane = tid & 63;
    const int wv   = tid >> 6;      // 0..7
    const int m16  = lane & 15;
    const int q    = lane >> 4;
    const int mi   = wv & 1;        // M-frag (rows mi*16..+16)
    const int ni   = wv >> 1;       // N-frag within 64-col supertile

    const int cw = tid & 63;        // staging col within supertile
    const int kb = (tid >> 6) * 32; // staging k-group

    // ---------------- phase 1b: GEMM over 5 supertiles of 64 cols ------------
    for (int nt = 0; nt < 5; nt++){
        {   // stage W^T tile: [64 cols][256 k] bf16 hi/lo
            int bcol = nt*64 + cw;
            const float* wp = nullptr; int wstr = 0;
            if (bcol < 256)      { wp = Wdt + bcol;       wstr = CC; }
            else if (bcol < 272) { wp = WB  + (bcol-256); wstr = SS; }
            else if (bcol < 288) { wp = WC  + (bcol-272); wstr = SS; }
            if (wp){
                #pragma unroll
                for (int i8 = 0; i8 < 32; i8 += 8){
                    unsigned short hs[8], ls[8];
                    #pragma unroll
                    for (int u = 0; u < 8; u++){
                        float v = wp[(size_t)(kb+i8+u)*wstr];
                        hs[u] = f2b(v);
                        ls[u] = f2b(v - b2f(hs[u]));
                    }
                    uint4 ph, pl;
                    ph.x = (unsigned)hs[0] | ((unsigned)hs[1] << 16);
                    ph.y = (unsigned)hs[2] | ((unsigned)hs[3] << 16);
                    ph.z = (unsigned)hs[4] | ((unsigned)hs[5] << 16);
                    ph.w = (unsigned)hs[6] | ((unsigned)hs[7] << 16);
                    pl.x = (unsigned)ls[0] | ((unsigned)ls[1] << 16);
                    pl.y = (unsigned)ls[2] | ((unsigned)ls[3] << 16);
                    pl.z = (unsigned)ls[4] | ((unsigned)ls[5] << 16);
                    pl.w = (unsigned)ls[6] | ((unsigned)ls[7] << 16);
                    *(uint4*)&Wh2[cw*WSTR + kb + i8] = ph;
                    *(uint4*)&Wl2[cw*WSTR + kb + i8] = pl;
                }
            }
        }
        __syncthreads();

        if (nt < 4 || ni < 2){
            floatx4 acc = (floatx4){0.f,0.f,0.f,0.f};
            #pragma unroll
            for (int ks = 0; ks < 256; ks += 32){
                short8 bh = *(const short8*)&Wh2[(ni*16+m16)*WSTR + ks + q*8];
                short8 bl = *(const short8*)&Wl2[(ni*16+m16)*WSTR + ks + q*8];
                short8 ah = *(const short8*)&xh [(mi*16+m16)*XSTR + ks + q*8];
                short8 al = *(const short8*)&xl [(mi*16+m16)*XSTR + ks + q*8];
                acc = __builtin_amdgcn_mfma_f32_16x16x32_bf16(al, bh, acc, 0, 0, 0);
                acc = __builtin_amdgcn_mfma_f32_16x16x32_bf16(ah, bl, acc, 0, 0, 0);
                acc = __builtin_amdgcn_mfma_f32_16x16x32_bf16(ah, bh, acc, 0, 0, 0);
            }
            int col   = nt*64 + ni*16 + m16;
            int rbase = mi*16 + q*4;
            if (col < 256){
                float bias = bdt[col];
                #pragma unroll
                for (int r=0;r<4;r++){
                    float v = softplus(0.01f + acc[r] + bias);
                    dtS[(rbase+r)*DSTR + col] = v;
                    dt[(size_t)(row0+rbase+r)*CC + col] = v;
                }
            } else if (col < 272){
                int s = col - 256;
                float A  = -fexp2(logA[s]*LOG2E);
                float sc = LOG2E / A;
                float bias = bB[s];
                #pragma unroll
                for (int r=0;r<4;r++){
                    float v = (1.f + acc[r] + bias) * sc;
                    boaS[(rbase+r)*SS + s] = v;
                    boa[(size_t)(row0+rbase+r)*SS + s] = v;
                }
            } else {
                int s = col - 272;
                float bias = bC[s];
                #pragma unroll
                for (int r=0;r<4;r++){
                    float v = acc[r] + bias;
                    cmS[(rbase+r)*SS + s] = v;
                    cm[(size_t)(row0+rbase+r)*SS + s] = v;
                }
            }
        }
        __syncthreads();
    }

    // ---------------- phase 2: local scan -> aggregates ----------------------
    const int c  = tid >> 1;        // channel 0..255
    const int sb = (tid & 1) * 8;   // state sub-block {0,8}

    float Al2v[8];
    #pragma unroll
    for (int i=0;i<8;i++) Al2v[i] = -fexp2(logA[sb+i]*LOG2E) * LOG2E;

    const float* __restrict__ xp = x + (size_t)row0*CC + c;

    float Apr[8], h[8];
    #pragma unroll
    for (int i=0;i<8;i++){ Apr[i]=1.f; h[i]=0.f; }

    #pragma unroll 8
    for (int t=0;t<TT;t++){
        float d  = dtS[t*DSTR + c];
        float xv = xp[(size_t)t*CC];
        float4 b0 = *(const float4*)&boaS[t*SS + sb];
        float4 b1 = *(const float4*)&boaS[t*SS + sb + 4];
        float bo[8] = {b0.x,b0.y,b0.z,b0.w,b1.x,b1.y,b1.z,b1.w};
        #pragma unroll
        for (int s=0;s<8;s++){
            float a = fexp2(d * Al2v[s]);
            float u = fexp2(fmaf(a, bo[s], -bo[s])) * xv;
            h[s] = fmaf(a, h[s], u);
            Apr[s] *= a;
        }
    }
    {
        const size_t base = (size_t)g*NJ + (size_t)c*SS + sb;
        *(float4*)&Ap[base]   = make_float4(Apr[0],Apr[1],Apr[2],Apr[3]);
        *(float4*)&Ap[base+4] = make_float4(Apr[4],Apr[5],Apr[6],Apr[7]);
        *(float4*)&Hl[base]   = make_float4(h[0],h[1],h[2],h[3]);
        *(float4*)&Hl[base+4] = make_float4(h[4],h[5],h[6],h[7]);
    }
}

// ============ K2: k_carry — seg-parallel scan, PER=16 in registers ===========
__global__ __launch_bounds__(256) void k_carry(const float* __restrict__ Ap,
    const float* __restrict__ Hl, float* __restrict__ Cr)
{
    const int tid = threadIdx.x;
    const int jl  = tid & 15;
    const int seg = tid >> 4;
    const int j   = blockIdx.x * 16 + jl;

    const size_t base = (size_t)(seg*PER)*NJ + j;

    float a[PER], u[PER];
    #pragma unroll
    for (int k=0;k<PER;k++){
        a[k] = Ap[base + (size_t)k*NJ];
        u[k] = Hl[base + (size_t)k*NJ];
    }
    float Aag = 1.f, Uag = 0.f;
    #pragma unroll
    for (int k=0;k<PER;k++){ Uag = fmaf(a[k], Uag, u[k]); Aag *= a[k]; }

    __shared__ float As[SEGS][17], Us[SEGS][17];
    As[seg][jl] = Aag; Us[seg][jl] = Uag;
    __syncthreads();
    float hin = 0.f;
    for (int t = 0; t < seg; ++t)
        hin = fmaf(As[t][jl], hin, Us[t][jl]);

    float h = hin;
    #pragma unroll
    for (int k=0;k<PER;k++){
        Cr[base + (size_t)k*NJ] = h;
        h = fmaf(a[k], h, u[k]);
    }
}

// ============ K3: k_scan2 — apply carry, contract to y (quad reduce) =========
__global__ __launch_bounds__(256) void k_scan2(const float* __restrict__ dt,
    const float* __restrict__ x, const float* __restrict__ boa,
    const float* __restrict__ cmat, const float* __restrict__ logA,
    const float* __restrict__ Cr, float* __restrict__ y)
{
    const int tid = threadIdx.x;
    const int sg  = tid & 3;
    const int cl  = tid >> 2;
    const int g   = blockIdx.x;
    const int c   = blockIdx.y * CB + cl;
    const int row0 = g * TT;

    float Al2[SP];
    #pragma unroll
    for (int i=0;i<SP;i++) Al2[i] = -fexp2(logA[sg*SP+i]*LOG2E) * LOG2E;

    const float* __restrict__ dp = dt   + (size_t)row0*CC + c;
    const float* __restrict__ xp = x    + (size_t)row0*CC + c;
    const float* __restrict__ bp = boa  + (size_t)row0*SS + sg*SP;
    const float* __restrict__ cp = cmat + (size_t)row0*SS + sg*SP;
    float* __restrict__ yp = y + (size_t)row0*CC + c;

    float h[SP];
    {
        float4 hc = *(const float4*)&Cr[(size_t)g*NJ + (size_t)c*SS + sg*SP];
        h[0]=hc.x; h[1]=hc.y; h[2]=hc.z; h[3]=hc.w;
    }

    #pragma unroll 8
    for (int t=0;t<TT;t++){
        float d  = dp[(size_t)t*CC];
        float xv = xp[(size_t)t*CC];
        float4 bo = *(const float4*)&bp[(size_t)t*SS];
        float4 cv = *(const float4*)&cp[(size_t)t*SS];
        float bov[SP] = {bo.x,bo.y,bo.z,bo.w};
        float cvv[SP] = {cv.x,cv.y,cv.z,cv.w};
        float yv = 0.f;
        #pragma unroll
        for (int s=0;s<SP;s++){
            float a = fexp2(d * Al2[s]);
            float u = fexp2(fmaf(a, bov[s], -bov[s])) * xv;
            h[s] = fmaf(a, h[s], u);
            yv = fmaf(cvv[s], h[s], yv);
        }
        yv += __shfl_xor(yv, 1);
        yv += __shfl_xor(yv, 2);
        if (sg == 0) yp[(size_t)t*CC] = yv;
    }
}

extern "C" void kernel_launch(void* const* d_in, const int* in_sizes, int n_in,
                              void* d_out, int out_size, void* d_ws, size_t ws_size,
                              hipStream_t stream) {
    const float* x    = (const float*)d_in[0];
    const float* logA = (const float*)d_in[1];
    const float* W_dt = (const float*)d_in[2];
    const float* b_dt = (const float*)d_in[3];
    const float* W_B  = (const float*)d_in[4];
    const float* b_B  = (const float*)d_in[5];
    const float* W_C  = (const float*)d_in[6];
    const float* b_C  = (const float*)d_in[7];
    float* y  = (float*)d_out;
    float* ws = (float*)d_ws;

    float* dt   = ws;                            // L*C   = 2M floats
    float* boa  = dt   + (size_t)LL*CC;          // L*S
    float* cmv  = boa  + (size_t)LL*SS;          // L*S
    float* Ap   = cmv  + (size_t)LL*SS;          // GG*NJ = 1M
    float* Hl   = Ap   + (size_t)GG*NJ;          // 1M
    float* Cr   = Hl   + (size_t)GG*NJ;          // 1M  (~21.5 MB total)

    hipLaunchKernelGGL(k_mmscan, dim3(GG), dim3(THREADS), 0, stream,
                       x, logA, W_dt, b_dt, W_B, b_B, W_C, b_C,
                       dt, boa, cmv, Ap, Hl);
    hipLaunchKernelGGL(k_carry, dim3(NJ/16), dim3(256), 0, stream, Ap, Hl, Cr);
    hipLaunchKernelGGL(k_scan2, dim3(GG,4), dim3(256), 0, stream,
                       dt, x, boa, cmv, logA, Cr, y);
}